// Round 6
// baseline (533.121 us; speedup 1.0000x reference)
//
#include <hip/hip_runtime.h>

#define BB 4
#define VV 256
#define HH 128
#define NROWS (BB*VV)            // 1024
#define NE_CNT (BB*VV*VV)        // 262144
#define EPSV 1e-5f

typedef float4 f4;

__device__ __forceinline__ float sigm(float x) {
    return 1.f / (1.f + __expf(-x));
}

#define COMP(v,kk) ((kk)==0 ? (v).x : (kk)==1 ? (v).y : (kk)==2 ? (v).z : (v).w)

// async HBM->LDS, 16B per lane; LDS dest = wave-uniform base + lane*16
#define GLOAD_LDS16(g, l) __builtin_amdgcn_global_load_lds( \
    (const __attribute__((address_space(1))) unsigned int*)(g), \
    (__attribute__((address_space(3))) unsigned int*)(l), 16, 0, 0)

// ---------------------------------------------------------------------------
// K1: Uh/Vh/Ah/Bh = h @ W{U,V,A,B}^T + b   (1024 x 128, K=128)
// ---------------------------------------------------------------------------
__global__ __launch_bounds__(256) void k_linear4(
    const float* __restrict__ h,
    const float* __restrict__ W0, const float* __restrict__ b0,
    const float* __restrict__ W1, const float* __restrict__ b1,
    const float* __restrict__ W2, const float* __restrict__ b2,
    const float* __restrict__ W3, const float* __restrict__ b3,
    float* __restrict__ out)
{
    __shared__ float hs[4*HH];
    const int tid = threadIdx.x;
    const int r0  = blockIdx.x * 4;
    if (tid < 128) {
        int r = tid >> 5, kq = (tid & 31) << 2;
        *(f4*)&hs[r*HH + kq] = *(const f4*)&h[(r0 + r)*HH + kq];
    }
    __syncthreads();
    const int n  = tid & 127;
    const int s0 = tid >> 7;                       // 0 or 1
    const float* Ws[4] = {W0, W1, W2, W3};
    const float* bs[4] = {b0, b1, b2, b3};
    for (int ss = 0; ss < 2; ++ss) {
        const int sel = s0 + ss*2;
        const float* wrow = Ws[sel] + n*HH;
        float a0=0.f, a1=0.f, a2=0.f, a3=0.f;
        for (int kq = 0; kq < 32; ++kq) {
            f4 w = *(const f4*)&wrow[kq<<2];
            float wq[4] = {w.x, w.y, w.z, w.w};
            #pragma unroll
            for (int q = 0; q < 4; ++q) {
                int k = (kq<<2) + q;
                float wv = wq[q];
                a0 += hs[0*HH + k] * wv;
                a1 += hs[1*HH + k] * wv;
                a2 += hs[2*HH + k] * wv;
                a3 += hs[3*HH + k] * wv;
            }
        }
        float bias = bs[sel][n];
        float* o = out + sel*(NROWS*HH);
        o[(r0+0)*HH + n] = a0 + bias;
        o[(r0+1)*HH + n] = a1 + bias;
        o[(r0+2)*HH + n] = a2 + bias;
        o[(r0+3)*HH + n] = a3 + bias;
    }
}

// ---------------------------------------------------------------------------
// K1b: WCt[k][n] = WC[n][k]  (128x128, LDS-tiled transpose)
// ---------------------------------------------------------------------------
__global__ __launch_bounds__(256) void k_transpose(
    const float* __restrict__ in, float* __restrict__ out)
{
    __shared__ float t[32][33];
    int ti = blockIdx.x >> 2, tj = blockIdx.x & 3;
    int tx = threadIdx.x & 31, ty = threadIdx.x >> 5;   // ty 0..7
    for (int yy = ty; yy < 32; yy += 8)
        t[yy][tx] = in[(ti*32 + yy)*HH + tj*32 + tx];
    __syncthreads();
    for (int yy = ty; yy < 32; yy += 8)
        out[(tj*32 + yy)*HH + ti*32 + tx] = t[tx][yy];
}

// ---------------------------------------------------------------------------
// K2 v7: BARRIER-FREE main loop.
//
// v6 post-mortem: traffic clean (scratch gone) but VALUBusy 36%, LDS busy
// ~33%, per-chunk critical path ~2-3x the pipe model -> barrier-lockstep +
// ds_read dependency stalls at ~8 waves/CU residency. Fix: the only SHARED
// operand is WCt (64 KB) -- stage it into LDS ONCE in the prologue; the
// streamed operand e is read directly from global (64B-line granular, L1
// hits for 3 of 4 k-groups; vmcnt independent of the LDS lgkmcnt for W).
// The K-loop then has ZERO __syncthreads: waves free-run at uncorrelated
// phases, hiding each other's latency.
//  - LDS = exactly 64 KB (wc 16384 floats; epilogue stats OVERLAY wc after
//    the loop, fenced by one barrier) -> 2 blocks/CU.
//  - ds_read volume halves vs v6 (only W reads): LDS floor ~41us < VALU
//    floor ~55us -> VALU-bound by construction.
//  - regs: acc 64 + aj 32 + w 8 + addr ~16 ~= 120 < 128 cap of (256,2).
// ---------------------------------------------------------------------------
__global__ __launch_bounds__(256, 2) void k_edge(
    const float* __restrict__ e, const int* __restrict__ A, const int* __restrict__ S,
    const float* __restrict__ WCt, const float* __restrict__ bC,
    const float* __restrict__ Ahw, const float* __restrict__ Bhw,
    const float* __restrict__ Vhw,
    float* __restrict__ eout, float* __restrict__ aggS, float* __restrict__ aggA,
    float* __restrict__ sums)
{
    __shared__ float wcs[HH*HH];         // 64 KB: WCt[k][n] linear; stats overlay later

    const int t     = threadIdx.x;
    const int bi    = blockIdx.x >> 1;       // b*V + i
    const int jbase = (blockIdx.x & 1) << 7; // 0 or 128
    const int b     = bi >> 8;

    const int tn  = t & 15;              // n = tn*4 + qq + q*64
    const int tjg = t >> 4;              // j = tjg + m*16   (tjg 0..15)

    // ---- prologue: stage entire WCt (128x128 f32) into LDS, linear ----
    {
        const f4* wct4 = (const f4*)WCt;
        const int wave = t >> 6;
        #pragma unroll
        for (int r = 0; r < 16; ++r)
            GLOAD_LDS16(wct4 + r*256 + t, &wcs[r*1024 + wave*256]);
    }
    __syncthreads();                     // drains DMA; only barrier before epilogue

    float acc[8][8];
    #pragma unroll
    for (int m = 0; m < 8; ++m)
        #pragma unroll
        for (int q = 0; q < 8; ++q) acc[m][q] = 0.f;

    const f4* erow = (const f4*)e + (size_t)(bi*VV + jbase)*32;  // + j*32 + ks

    // ---- K loop: 32 f4-groups of k; NO barriers ----
    for (int ks = 0; ks < 32; ++ks) {
        f4 aj[8];
        #pragma unroll
        for (int m = 0; m < 8; ++m)
            aj[m] = erow[(size_t)(tjg + m*16)*32 + ks];
        #pragma unroll
        for (int kk = 0; kk < 4; ++kk) {
            const float* wrow = &wcs[(ks*4 + kk)*128 + tn*4];
            f4 w0 = *(const f4*)&wrow[0];
            f4 w1 = *(const f4*)&wrow[64];
            #pragma unroll
            for (int m = 0; m < 8; ++m) {
                float a = COMP(aj[m], kk);
                acc[m][0] += a*w0.x; acc[m][1] += a*w0.y;
                acc[m][2] += a*w0.z; acc[m][3] += a*w0.w;
                acc[m][4] += a*w1.x; acc[m][5] += a*w1.y;
                acc[m][6] += a*w1.z; acc[m][7] += a*w1.w;
            }
        }
    }

    // ---- epilogue: e_new = acc + bC + Bh[i] + Ah[j]; store; stats; aggs ----
    __syncthreads();                     // all FMAs done -> wc dead; overlay stats
    float* s_aggS = wcs;
    float* s_aggA = wcs + 128;
    float* s_sum  = wcs + 256;
    float* s_ssq  = wcs + 384;
    if (t < HH) { s_aggS[t]=0.f; s_aggA[t]=0.f; s_sum[t]=0.f; s_ssq[t]=0.f; }
    __syncthreads();

    float bcv[8], bhv[8];
    #pragma unroll
    for (int q = 0; q < 2; ++q) {
        f4 bc4 = *(const f4*)&bC[tn*4 + q*64];
        f4 bh4 = *(const f4*)&Bhw[bi*HH + tn*4 + q*64];
        bcv[q*4+0]=bc4.x; bcv[q*4+1]=bc4.y; bcv[q*4+2]=bc4.z; bcv[q*4+3]=bc4.w;
        bhv[q*4+0]=bh4.x; bhv[q*4+1]=bh4.y; bhv[q*4+2]=bh4.z; bhv[q*4+3]=bh4.w;
    }
    float sm[8], sq[8], aS[8], aA[8];
    #pragma unroll
    for (int q = 0; q < 8; ++q) { sm[q]=0.f; sq[q]=0.f; aS[q]=0.f; aA[q]=0.f; }

    const int* Sp = S + bi*VV + jbase;
    const int* Ap = A + bi*VV + jbase;
    #pragma unroll
    for (int jj = 0; jj < 8; ++jj) {
        const int j = tjg + jj*16;               // local j in [0,128)
        const int jg = jbase + j;                // global j
        const float* ahp = &Ahw[(size_t)(b*VV + jg)*HH];
        const float* vhp = &Vhw[(size_t)(b*VV + jg)*HH];
        const int Sij = Sp[j], Aij = Ap[j];
        #pragma unroll
        for (int q = 0; q < 2; ++q) {
            f4 ah = *(const f4*)&ahp[tn*4 + q*64];
            f4 vh = *(const f4*)&vhp[tn*4 + q*64];
            f4 env;
            env.x = acc[jj][q*4+0] + bcv[q*4+0] + bhv[q*4+0] + ah.x;
            env.y = acc[jj][q*4+1] + bcv[q*4+1] + bhv[q*4+1] + ah.y;
            env.z = acc[jj][q*4+2] + bcv[q*4+2] + bhv[q*4+2] + ah.z;
            env.w = acc[jj][q*4+3] + bcv[q*4+3] + bhv[q*4+3] + ah.w;
            *(f4*)&eout[((size_t)(bi*VV) + jg)*HH + tn*4 + q*64] = env;
            float vv[4] = {vh.x, vh.y, vh.z, vh.w};
            float ev[4] = {env.x, env.y, env.z, env.w};
            #pragma unroll
            for (int qq = 0; qq < 4; ++qq) {
                float v = ev[qq];
                sm[q*4+qq] += v;
                sq[q*4+qq] += v*v;
                if (!Aij) aA[q*4+qq] += vv[qq];
                if (!Sij) aS[q*4+qq] += vv[qq] * sigm(v);
            }
        }
    }
    #pragma unroll
    for (int q = 0; q < 2; ++q)
        #pragma unroll
        for (int qq = 0; qq < 4; ++qq) {
            int n = tn*4 + q*64 + qq;
            atomicAdd(&s_sum[n],  sm[q*4+qq]);
            atomicAdd(&s_ssq[n],  sq[q*4+qq]);
            atomicAdd(&s_aggS[n], aS[q*4+qq]);
            atomicAdd(&s_aggA[n], aA[q*4+qq]);
        }
    __syncthreads();
    if (t < HH) {
        atomicAdd(&aggS[bi*HH + t], s_aggS[t]);
        atomicAdd(&aggA[bi*HH + t], s_aggA[t]);
        atomicAdd(&sums[t],      s_sum[t]);   // e channel sum
        atomicAdd(&sums[HH + t], s_ssq[t]);   // e channel sumsq
    }
}

// ---------------------------------------------------------------------------
// K3a: h_new = Uh + aggS + aggA ; accumulate h channel sums
// ---------------------------------------------------------------------------
__global__ __launch_bounds__(256) void k_hnew(
    const float* __restrict__ Uh, const float* __restrict__ aggS,
    const float* __restrict__ aggA, float* __restrict__ h_new,
    float* __restrict__ sums)
{
    __shared__ float ssm[HH], ssq[HH];
    const int tid = threadIdx.x;
    if (tid < 128) { ssm[tid]=0.f; ssq[tid]=0.f; }
    __syncthreads();
    int gid = blockIdx.x*256 + tid;
    f4 u = *(const f4*)&Uh[gid*4];
    f4 s = *(const f4*)&aggS[gid*4];
    f4 a = *(const f4*)&aggA[gid*4];
    float v0=u.x+s.x+a.x, v1=u.y+s.y+a.y, v2=u.z+s.z+a.z, v3=u.w+s.w+a.w;
    *(f4*)&h_new[gid*4] = make_float4(v0,v1,v2,v3);
    int n0 = (gid*4) & 127;
    atomicAdd(&ssm[n0+0], v0); atomicAdd(&ssq[n0+0], v0*v0);
    atomicAdd(&ssm[n0+1], v1); atomicAdd(&ssq[n0+1], v1*v1);
    atomicAdd(&ssm[n0+2], v2); atomicAdd(&ssq[n0+2], v2*v2);
    atomicAdd(&ssm[n0+3], v3); atomicAdd(&ssq[n0+3], v3*v3);
    __syncthreads();
    if (tid < 128) {
        atomicAdd(&sums[256 + tid], ssm[tid]);
        atomicAdd(&sums[384 + tid], ssq[tid]);
    }
}

// ---------------------------------------------------------------------------
// K3b: finalize batchnorm params -> scale/shift per channel
// ---------------------------------------------------------------------------
__global__ void k_stats(const float* __restrict__ sums, float* __restrict__ outs,
                        const float* __restrict__ gamma_e, const float* __restrict__ beta_e,
                        const float* __restrict__ gamma_h, const float* __restrict__ beta_h)
{
    int n = threadIdx.x;   // 128
    float em  = sums[n] * (1.f/(float)NE_CNT);
    float ev  = sums[128+n] * (1.f/(float)NE_CNT) - em*em;
    float esc = rsqrtf(ev + EPSV) * gamma_e[n];
    outs[n]       = esc;
    outs[128 + n] = beta_e[n] - em*esc;
    float hm  = sums[256+n] * (1.f/1024.f);
    float hv  = sums[384+n] * (1.f/1024.f) - hm*hm;
    float hsc = rsqrtf(hv + EPSV) * gamma_h[n];
    outs[256 + n] = hsc;
    outs[384 + n] = beta_h[n] - hm*hsc;
}

// ---------------------------------------------------------------------------
// K4h: h_out = h_in + relu(bn(h_new))
// ---------------------------------------------------------------------------
__global__ __launch_bounds__(256) void k_hout(
    const float* __restrict__ h_in, const float* __restrict__ h_new,
    const float* __restrict__ outs, float* __restrict__ hout)
{
    int gid = blockIdx.x*256 + threadIdx.x;
    int n0 = (gid*4) & 127;
    f4 x  = *(const f4*)&h_new[gid*4];
    f4 hi = *(const f4*)&h_in[gid*4];
    f4 sc = *(const f4*)&outs[256 + n0];
    f4 sh = *(const f4*)&outs[384 + n0];
    f4 y;
    y.x = fmaxf(x.x*sc.x + sh.x, 0.f) + hi.x;
    y.y = fmaxf(x.y*sc.y + sh.y, 0.f) + hi.y;
    y.z = fmaxf(x.z*sc.z + sh.z, 0.f) + hi.z;
    y.w = fmaxf(x.w*sc.w + sh.w, 0.f) + hi.w;
    *(f4*)&hout[gid*4] = y;
}

// ---------------------------------------------------------------------------
// K4e: e_out = e_in + relu(bn(e_new))   (e_new lives in-place in d_out)
// ---------------------------------------------------------------------------
__global__ __launch_bounds__(256) void k_eout(
    const float* __restrict__ e_in, const float* __restrict__ outs,
    float* __restrict__ eio)
{
    size_t gid = (size_t)blockIdx.x*256 + threadIdx.x;
    int n0 = ((int)(gid & 31)) << 2;
    f4 x  = *(const f4*)&eio[gid*4];
    f4 ei = *(const f4*)&e_in[gid*4];
    f4 sc = *(const f4*)&outs[n0];
    f4 sh = *(const f4*)&outs[128 + n0];
    f4 y;
    y.x = fmaxf(x.x*sc.x + sh.x, 0.f) + ei.x;
    y.y = fmaxf(x.y*sc.y + sh.y, 0.f) + ei.y;
    y.z = fmaxf(x.z*sc.z + sh.z, 0.f) + ei.z;
    y.w = fmaxf(x.w*sc.w + sh.w, 0.f) + ei.w;
    *(f4*)&eio[gid*4] = y;
}

// ---------------------------------------------------------------------------
extern "C" void kernel_launch(void* const* d_in, const int* in_sizes, int n_in,
                              void* d_out, int out_size, void* d_ws, size_t ws_size,
                              hipStream_t stream)
{
    (void)in_sizes; (void)n_in; (void)out_size; (void)ws_size;
    const float* h   = (const float*)d_in[0];
    const float* e   = (const float*)d_in[1];
    const int*   A   = (const int*)d_in[2];
    const int*   S   = (const int*)d_in[3];
    const float* WU  = (const float*)d_in[4];   const float* bU = (const float*)d_in[5];
    const float* WV  = (const float*)d_in[6];   const float* bV = (const float*)d_in[7];
    const float* WA_ = (const float*)d_in[8];   const float* bA = (const float*)d_in[9];
    const float* WB_ = (const float*)d_in[10];  const float* bB = (const float*)d_in[11];
    const float* WC_ = (const float*)d_in[12];  const float* bC = (const float*)d_in[13];
    const float* gamma_h = (const float*)d_in[14]; const float* beta_h = (const float*)d_in[15];
    const float* gamma_e = (const float*)d_in[16]; const float* beta_e = (const float*)d_in[17];

    float* ws    = (float*)d_ws;
    float* Uh    = ws;              // 1024*128
    float* Vh    = ws + 131072;
    float* Ahw   = ws + 262144;
    float* Bhw   = ws + 393216;
    float* aggS  = ws + 524288;
    float* aggA  = ws + 655360;
    float* h_new = ws + 786432;
    float* WCt   = ws + 917504;     // 128*128
    float* sums  = ws + 933888;     // 512: e_sum, e_ssq, h_sum, h_ssq
    float* outs  = ws + 934400;     // 512: e_scale, e_shift, h_scale, h_shift

    float* hout = (float*)d_out;
    float* eout = (float*)d_out + NROWS*HH;     // e_new then e_out, in place

    hipMemsetAsync(sums, 0, 512*sizeof(float), stream);
    hipMemsetAsync(aggS, 0, 262144*sizeof(float), stream);  // aggS+aggA (contig)
    k_linear4 <<<256,   256, 0, stream>>>(h, WU,bU, WV,bV, WA_,bA, WB_,bB, Uh);
    k_transpose<<<16,   256, 0, stream>>>(WC_, WCt);
    k_edge    <<<2048,  256, 0, stream>>>(e, A, S, WCt, bC, Ahw, Bhw, Vh,
                                          eout, aggS, aggA, sums);
    k_hnew    <<<128,   256, 0, stream>>>(Uh, aggS, aggA, h_new, sums);
    k_stats   <<<1,     128, 0, stream>>>(sums, outs, gamma_e, beta_e, gamma_h, beta_h);
    k_hout    <<<128,   256, 0, stream>>>(h, h_new, outs, hout);
    k_eout    <<<32768, 256, 0, stream>>>(e, outs, eout);
}

// Round 7
// 517.634 us; speedup vs baseline: 1.0299x; 1.0299x over previous
//
#include <hip/hip_runtime.h>

#define BB 4
#define VV 256
#define HH 128
#define NROWS (BB*VV)            // 1024
#define NE_CNT (BB*VV*VV)        // 262144
#define EPSV 1e-5f

typedef float4 f4;

__device__ __forceinline__ float sigm(float x) {
    return 1.f / (1.f + __expf(-x));
}

#define COMP(v,kk) ((kk)==0 ? (v).x : (kk)==1 ? (v).y : (kk)==2 ? (v).z : (v).w)

// async HBM->LDS, 16B per lane; LDS dest = wave-uniform base + lane*16
#define GLOAD_LDS16(g, l) __builtin_amdgcn_global_load_lds( \
    (const __attribute__((address_space(1))) unsigned int*)(g), \
    (__attribute__((address_space(3))) unsigned int*)(l), 16, 0, 0)

// ---------------------------------------------------------------------------
// K1: Uh/Vh/Ah/Bh = h @ W{U,V,A,B}^T + b   (1024 x 128, K=128)
// ---------------------------------------------------------------------------
__global__ __launch_bounds__(256) void k_linear4(
    const float* __restrict__ h,
    const float* __restrict__ W0, const float* __restrict__ b0,
    const float* __restrict__ W1, const float* __restrict__ b1,
    const float* __restrict__ W2, const float* __restrict__ b2,
    const float* __restrict__ W3, const float* __restrict__ b3,
    float* __restrict__ out)
{
    __shared__ float hs[4*HH];
    const int tid = threadIdx.x;
    const int r0  = blockIdx.x * 4;
    if (tid < 128) {
        int r = tid >> 5, kq = (tid & 31) << 2;
        *(f4*)&hs[r*HH + kq] = *(const f4*)&h[(r0 + r)*HH + kq];
    }
    __syncthreads();
    const int n  = tid & 127;
    const int s0 = tid >> 7;                       // 0 or 1
    const float* Ws[4] = {W0, W1, W2, W3};
    const float* bs[4] = {b0, b1, b2, b3};
    for (int ss = 0; ss < 2; ++ss) {
        const int sel = s0 + ss*2;
        const float* wrow = Ws[sel] + n*HH;
        float a0=0.f, a1=0.f, a2=0.f, a3=0.f;
        for (int kq = 0; kq < 32; ++kq) {
            f4 w = *(const f4*)&wrow[kq<<2];
            float wq[4] = {w.x, w.y, w.z, w.w};
            #pragma unroll
            for (int q = 0; q < 4; ++q) {
                int k = (kq<<2) + q;
                float wv = wq[q];
                a0 += hs[0*HH + k] * wv;
                a1 += hs[1*HH + k] * wv;
                a2 += hs[2*HH + k] * wv;
                a3 += hs[3*HH + k] * wv;
            }
        }
        float bias = bs[sel][n];
        float* o = out + sel*(NROWS*HH);
        o[(r0+0)*HH + n] = a0 + bias;
        o[(r0+1)*HH + n] = a1 + bias;
        o[(r0+2)*HH + n] = a2 + bias;
        o[(r0+3)*HH + n] = a3 + bias;
    }
}

// ---------------------------------------------------------------------------
// K1b: WCt[k][n] = WC[n][k]  (128x128, LDS-tiled transpose)
// ---------------------------------------------------------------------------
__global__ __launch_bounds__(256) void k_transpose(
    const float* __restrict__ in, float* __restrict__ out)
{
    __shared__ float t[32][33];
    int ti = blockIdx.x >> 2, tj = blockIdx.x & 3;
    int tx = threadIdx.x & 31, ty = threadIdx.x >> 5;   // ty 0..7
    for (int yy = ty; yy < 32; yy += 8)
        t[yy][tx] = in[(ti*32 + yy)*HH + tj*32 + tx];
    __syncthreads();
    for (int yy = ty; yy < 32; yy += 8)
        out[(tj*32 + yy)*HH + ti*32 + tx] = t[tx][yy];
}

// ---------------------------------------------------------------------------
// K2 v8: barrier-free + explicit register double-buffer on the e operand.
//
// v7 post-mortem: VGPR=88 -- without pressure headroom the compiler split
// the 8 aj loads into 2 groups of 4, re-serializing load->FMA; exposed
// cold-e latency at 2 waves/SIMD kept VALUBusy at 33%. Fix:
//  - ajA[8]/ajB[8] explicit 1-iteration software pipeline (static indexing,
//    ks-loop unrolled x2): 8 independent loads issue a full 512-cyc FMA
//    block ahead of their use.
//  - __launch_bounds__(256,1): allocator law cap=256/arg -> ~256 VGPR room;
//    need ~150 (acc 64 + ajA/ajB 64 + addr ~20). LDS 64KB already caps
//    residency at 2 blocks/CU, so the register headroom costs nothing.
//  - W resident whole in LDS (64KB, staged once via gload_lds); e read
//    directly from global (streamed, zero reuse -> no LDS staging); NO
//    barriers in the K loop.
// ---------------------------------------------------------------------------
__global__ __launch_bounds__(256, 1) void k_edge(
    const float* __restrict__ e, const int* __restrict__ A, const int* __restrict__ S,
    const float* __restrict__ WCt, const float* __restrict__ bC,
    const float* __restrict__ Ahw, const float* __restrict__ Bhw,
    const float* __restrict__ Vhw,
    float* __restrict__ eout, float* __restrict__ aggS, float* __restrict__ aggA,
    float* __restrict__ sums)
{
    __shared__ float wcs[HH*HH];         // 64 KB: WCt[k][n] linear; stats overlay later

    const int t     = threadIdx.x;
    const int bi    = blockIdx.x >> 1;       // b*V + i
    const int jbase = (blockIdx.x & 1) << 7; // 0 or 128
    const int b     = bi >> 8;

    const int tn  = t & 15;              // n = tn*4 + qq + q*64
    const int tjg = t >> 4;              // j = tjg + m*16   (tjg 0..15)

    // ---- prologue: stage entire WCt (128x128 f32) into LDS, linear ----
    {
        const f4* wct4 = (const f4*)WCt;
        const int wave = t >> 6;
        #pragma unroll
        for (int r = 0; r < 16; ++r)
            GLOAD_LDS16(wct4 + r*256 + t, &wcs[r*1024 + wave*256]);
    }
    __syncthreads();                     // drains DMA; only barrier before epilogue

    float acc[8][8];
    #pragma unroll
    for (int m = 0; m < 8; ++m)
        #pragma unroll
        for (int q = 0; q < 8; ++q) acc[m][q] = 0.f;

    const f4* erow = (const f4*)e + (size_t)(bi*VV + jbase)*32;  // + j*32 + ks

    #define FMA_STEP(AJ, KS) do {                                       \
        _Pragma("unroll")                                               \
        for (int kk = 0; kk < 4; ++kk) {                                \
            const float* wrow = &wcs[((KS)*4 + kk)*128 + tn*4];         \
            f4 w0 = *(const f4*)&wrow[0];                               \
            f4 w1 = *(const f4*)&wrow[64];                              \
            _Pragma("unroll")                                           \
            for (int m = 0; m < 8; ++m) {                               \
                float a = COMP(AJ[m], kk);                              \
                acc[m][0] += a*w0.x; acc[m][1] += a*w0.y;               \
                acc[m][2] += a*w0.z; acc[m][3] += a*w0.w;               \
                acc[m][4] += a*w1.x; acc[m][5] += a*w1.y;               \
                acc[m][6] += a*w1.z; acc[m][7] += a*w1.w;               \
            }                                                           \
        }                                                               \
    } while (0)

    // ---- K loop: 32 f4-groups of k; reg-dbuf pipeline; NO barriers ----
    f4 ajA[8], ajB[8];
    #pragma unroll
    for (int m = 0; m < 8; ++m)
        ajA[m] = erow[(size_t)(tjg + m*16)*32 + 0];

    for (int ks = 0; ks < 32; ks += 2) {
        #pragma unroll
        for (int m = 0; m < 8; ++m)                  // prefetch ks+1
            ajB[m] = erow[(size_t)(tjg + m*16)*32 + ks + 1];
        FMA_STEP(ajA, ks);
        if (ks + 2 < 32) {
            #pragma unroll
            for (int m = 0; m < 8; ++m)              // prefetch ks+2
                ajA[m] = erow[(size_t)(tjg + m*16)*32 + ks + 2];
        }
        FMA_STEP(ajB, ks + 1);
    }
    #undef FMA_STEP

    // ---- epilogue: e_new = acc + bC + Bh[i] + Ah[j]; store; stats; aggs ----
    __syncthreads();                     // all FMAs done -> wc dead; overlay stats
    float* s_aggS = wcs;
    float* s_aggA = wcs + 128;
    float* s_sum  = wcs + 256;
    float* s_ssq  = wcs + 384;
    if (t < HH) { s_aggS[t]=0.f; s_aggA[t]=0.f; s_sum[t]=0.f; s_ssq[t]=0.f; }
    __syncthreads();

    float bcv[8], bhv[8];
    #pragma unroll
    for (int q = 0; q < 2; ++q) {
        f4 bc4 = *(const f4*)&bC[tn*4 + q*64];
        f4 bh4 = *(const f4*)&Bhw[bi*HH + tn*4 + q*64];
        bcv[q*4+0]=bc4.x; bcv[q*4+1]=bc4.y; bcv[q*4+2]=bc4.z; bcv[q*4+3]=bc4.w;
        bhv[q*4+0]=bh4.x; bhv[q*4+1]=bh4.y; bhv[q*4+2]=bh4.z; bhv[q*4+3]=bh4.w;
    }
    float sm[8], sq[8], aS[8], aA[8];
    #pragma unroll
    for (int q = 0; q < 8; ++q) { sm[q]=0.f; sq[q]=0.f; aS[q]=0.f; aA[q]=0.f; }

    const int* Sp = S + bi*VV + jbase;
    const int* Ap = A + bi*VV + jbase;
    #pragma unroll
    for (int jj = 0; jj < 8; ++jj) {
        const int j = tjg + jj*16;               // local j in [0,128)
        const int jg = jbase + j;                // global j
        const float* ahp = &Ahw[(size_t)(b*VV + jg)*HH];
        const float* vhp = &Vhw[(size_t)(b*VV + jg)*HH];
        const int Sij = Sp[j], Aij = Ap[j];
        #pragma unroll
        for (int q = 0; q < 2; ++q) {
            f4 ah = *(const f4*)&ahp[tn*4 + q*64];
            f4 vh = *(const f4*)&vhp[tn*4 + q*64];
            f4 env;
            env.x = acc[jj][q*4+0] + bcv[q*4+0] + bhv[q*4+0] + ah.x;
            env.y = acc[jj][q*4+1] + bcv[q*4+1] + bhv[q*4+1] + ah.y;
            env.z = acc[jj][q*4+2] + bcv[q*4+2] + bhv[q*4+2] + ah.z;
            env.w = acc[jj][q*4+3] + bcv[q*4+3] + bhv[q*4+3] + ah.w;
            *(f4*)&eout[((size_t)(bi*VV) + jg)*HH + tn*4 + q*64] = env;
            float vv[4] = {vh.x, vh.y, vh.z, vh.w};
            float ev[4] = {env.x, env.y, env.z, env.w};
            #pragma unroll
            for (int qq = 0; qq < 4; ++qq) {
                float v = ev[qq];
                sm[q*4+qq] += v;
                sq[q*4+qq] += v*v;
                if (!Aij) aA[q*4+qq] += vv[qq];
                if (!Sij) aS[q*4+qq] += vv[qq] * sigm(v);
            }
        }
    }
    #pragma unroll
    for (int q = 0; q < 2; ++q)
        #pragma unroll
        for (int qq = 0; qq < 4; ++qq) {
            int n = tn*4 + q*64 + qq;
            atomicAdd(&s_sum[n],  sm[q*4+qq]);
            atomicAdd(&s_ssq[n],  sq[q*4+qq]);
            atomicAdd(&s_aggS[n], aS[q*4+qq]);
            atomicAdd(&s_aggA[n], aA[q*4+qq]);
        }
    __syncthreads();
    if (t < HH) {
        atomicAdd(&aggS[bi*HH + t], s_aggS[t]);
        atomicAdd(&aggA[bi*HH + t], s_aggA[t]);
        atomicAdd(&sums[t],      s_sum[t]);   // e channel sum
        atomicAdd(&sums[HH + t], s_ssq[t]);   // e channel sumsq
    }
}

// ---------------------------------------------------------------------------
// K3a: h_new = Uh + aggS + aggA ; accumulate h channel sums
// ---------------------------------------------------------------------------
__global__ __launch_bounds__(256) void k_hnew(
    const float* __restrict__ Uh, const float* __restrict__ aggS,
    const float* __restrict__ aggA, float* __restrict__ h_new,
    float* __restrict__ sums)
{
    __shared__ float ssm[HH], ssq[HH];
    const int tid = threadIdx.x;
    if (tid < 128) { ssm[tid]=0.f; ssq[tid]=0.f; }
    __syncthreads();
    int gid = blockIdx.x*256 + tid;
    f4 u = *(const f4*)&Uh[gid*4];
    f4 s = *(const f4*)&aggS[gid*4];
    f4 a = *(const f4*)&aggA[gid*4];
    float v0=u.x+s.x+a.x, v1=u.y+s.y+a.y, v2=u.z+s.z+a.z, v3=u.w+s.w+a.w;
    *(f4*)&h_new[gid*4] = make_float4(v0,v1,v2,v3);
    int n0 = (gid*4) & 127;
    atomicAdd(&ssm[n0+0], v0); atomicAdd(&ssq[n0+0], v0*v0);
    atomicAdd(&ssm[n0+1], v1); atomicAdd(&ssq[n0+1], v1*v1);
    atomicAdd(&ssm[n0+2], v2); atomicAdd(&ssq[n0+2], v2*v2);
    atomicAdd(&ssm[n0+3], v3); atomicAdd(&ssq[n0+3], v3*v3);
    __syncthreads();
    if (tid < 128) {
        atomicAdd(&sums[256 + tid], ssm[tid]);
        atomicAdd(&sums[384 + tid], ssq[tid]);
    }
}

// ---------------------------------------------------------------------------
// K3b: finalize batchnorm params -> scale/shift per channel
// ---------------------------------------------------------------------------
__global__ void k_stats(const float* __restrict__ sums, float* __restrict__ outs,
                        const float* __restrict__ gamma_e, const float* __restrict__ beta_e,
                        const float* __restrict__ gamma_h, const float* __restrict__ beta_h)
{
    int n = threadIdx.x;   // 128
    float em  = sums[n] * (1.f/(float)NE_CNT);
    float ev  = sums[128+n] * (1.f/(float)NE_CNT) - em*em;
    float esc = rsqrtf(ev + EPSV) * gamma_e[n];
    outs[n]       = esc;
    outs[128 + n] = beta_e[n] - em*esc;
    float hm  = sums[256+n] * (1.f/1024.f);
    float hv  = sums[384+n] * (1.f/1024.f) - hm*hm;
    float hsc = rsqrtf(hv + EPSV) * gamma_h[n];
    outs[256 + n] = hsc;
    outs[384 + n] = beta_h[n] - hm*hsc;
}

// ---------------------------------------------------------------------------
// K4h: h_out = h_in + relu(bn(h_new))
// ---------------------------------------------------------------------------
__global__ __launch_bounds__(256) void k_hout(
    const float* __restrict__ h_in, const float* __restrict__ h_new,
    const float* __restrict__ outs, float* __restrict__ hout)
{
    int gid = blockIdx.x*256 + threadIdx.x;
    int n0 = (gid*4) & 127;
    f4 x  = *(const f4*)&h_new[gid*4];
    f4 hi = *(const f4*)&h_in[gid*4];
    f4 sc = *(const f4*)&outs[256 + n0];
    f4 sh = *(const f4*)&outs[384 + n0];
    f4 y;
    y.x = fmaxf(x.x*sc.x + sh.x, 0.f) + hi.x;
    y.y = fmaxf(x.y*sc.y + sh.y, 0.f) + hi.y;
    y.z = fmaxf(x.z*sc.z + sh.z, 0.f) + hi.z;
    y.w = fmaxf(x.w*sc.w + sh.w, 0.f) + hi.w;
    *(f4*)&hout[gid*4] = y;
}

// ---------------------------------------------------------------------------
// K4e: e_out = e_in + relu(bn(e_new))   (e_new lives in-place in d_out)
// ---------------------------------------------------------------------------
__global__ __launch_bounds__(256) void k_eout(
    const float* __restrict__ e_in, const float* __restrict__ outs,
    float* __restrict__ eio)
{
    size_t gid = (size_t)blockIdx.x*256 + threadIdx.x;
    int n0 = ((int)(gid & 31)) << 2;
    f4 x  = *(const f4*)&eio[gid*4];
    f4 ei = *(const f4*)&e_in[gid*4];
    f4 sc = *(const f4*)&outs[n0];
    f4 sh = *(const f4*)&outs[128 + n0];
    f4 y;
    y.x = fmaxf(x.x*sc.x + sh.x, 0.f) + ei.x;
    y.y = fmaxf(x.y*sc.y + sh.y, 0.f) + ei.y;
    y.z = fmaxf(x.z*sc.z + sh.z, 0.f) + ei.z;
    y.w = fmaxf(x.w*sc.w + sh.w, 0.f) + ei.w;
    *(f4*)&eio[gid*4] = y;
}

// ---------------------------------------------------------------------------
extern "C" void kernel_launch(void* const* d_in, const int* in_sizes, int n_in,
                              void* d_out, int out_size, void* d_ws, size_t ws_size,
                              hipStream_t stream)
{
    (void)in_sizes; (void)n_in; (void)out_size; (void)ws_size;
    const float* h   = (const float*)d_in[0];
    const float* e   = (const float*)d_in[1];
    const int*   A   = (const int*)d_in[2];
    const int*   S   = (const int*)d_in[3];
    const float* WU  = (const float*)d_in[4];   const float* bU = (const float*)d_in[5];
    const float* WV  = (const float*)d_in[6];   const float* bV = (const float*)d_in[7];
    const float* WA_ = (const float*)d_in[8];   const float* bA = (const float*)d_in[9];
    const float* WB_ = (const float*)d_in[10];  const float* bB = (const float*)d_in[11];
    const float* WC_ = (const float*)d_in[12];  const float* bC = (const float*)d_in[13];
    const float* gamma_h = (const float*)d_in[14]; const float* beta_h = (const float*)d_in[15];
    const float* gamma_e = (const float*)d_in[16]; const float* beta_e = (const float*)d_in[17];

    float* ws    = (float*)d_ws;
    float* Uh    = ws;              // 1024*128
    float* Vh    = ws + 131072;
    float* Ahw   = ws + 262144;
    float* Bhw   = ws + 393216;
    float* aggS  = ws + 524288;
    float* aggA  = ws + 655360;
    float* h_new = ws + 786432;
    float* WCt   = ws + 917504;     // 128*128
    float* sums  = ws + 933888;     // 512: e_sum, e_ssq, h_sum, h_ssq
    float* outs  = ws + 934400;     // 512: e_scale, e_shift, h_scale, h_shift

    float* hout = (float*)d_out;
    float* eout = (float*)d_out + NROWS*HH;     // e_new then e_out, in place

    hipMemsetAsync(sums, 0, 512*sizeof(float), stream);
    hipMemsetAsync(aggS, 0, 262144*sizeof(float), stream);  // aggS+aggA (contig)
    k_linear4 <<<256,   256, 0, stream>>>(h, WU,bU, WV,bV, WA_,bA, WB_,bB, Uh);
    k_transpose<<<16,   256, 0, stream>>>(WC_, WCt);
    k_edge    <<<2048,  256, 0, stream>>>(e, A, S, WCt, bC, Ahw, Bhw, Vh,
                                          eout, aggS, aggA, sums);
    k_hnew    <<<128,   256, 0, stream>>>(Uh, aggS, aggA, h_new, sums);
    k_stats   <<<1,     128, 0, stream>>>(sums, outs, gamma_e, beta_e, gamma_h, beta_h);
    k_hout    <<<128,   256, 0, stream>>>(h, h_new, outs, hout);
    k_eout    <<<32768, 256, 0, stream>>>(e, outs, eout);
}